// Round 8
// baseline (192.897 us; speedup 1.0000x reference)
//
#include <hip/hip_runtime.h>

typedef float f32x16 __attribute__((ext_vector_type(16)));
typedef short bf16x8 __attribute__((ext_vector_type(8)));
typedef unsigned int u32;

static __device__ __forceinline__ unsigned short f2bf(float f) {
  union { float f; unsigned int u; } v;
  v.f = f;
  return (unsigned short)((v.u + 0x7FFFu + ((v.u >> 16) & 1u)) >> 16);
}

// async 16B global->LDS (DMA). LDS dest = wave-uniform base + lane*16.
static __device__ __forceinline__ void gl_lds16(const unsigned short* g,
                                                unsigned short* l) {
  __builtin_amdgcn_global_load_lds(
      (const __attribute__((address_space(1))) u32*)g,
      (__attribute__((address_space(3))) u32*)l, 16, 0, 0);
}

// ---- weights: OIHW fp32 -> [cic][p][tap][co][8ci] bf16 (contiguous; a
// wave's per-tap A-frag load = 2x 512B coalesced segments); + zero page.
__global__ __launch_bounds__(256) void convert_weights(
    const float* __restrict__ W1, const float* __restrict__ W2,
    unsigned short* __restrict__ W1b, unsigned short* __restrict__ W2b,
    unsigned short* __restrict__ zp) {
  if (blockIdx.x == 1728) {
    uint4* z = (uint4*)zp;
    z[threadIdx.x] = make_uint4(0, 0, 0, 0);
    z[256 + threadIdx.x] = make_uint4(0, 0, 0, 0);
    return;
  }
  int i = blockIdx.x * 256 + threadIdx.x;
  if (i < 294912) {
    int e = i & 7, co = (i >> 3) & 127, r = i >> 10;  // r=(cic*2+p)*9+tap
    int tap = r % 9, pc = r / 9;
    int ci = (pc >> 1) * 16 + (pc & 1) * 8 + e;
    W1b[i] = f2bf(W1[(co * 256 + ci) * 9 + tap]);
  } else {
    int j = i - 294912;
    if (j < 147456) {
      int e = j & 7, co = (j >> 3) & 127, r = j >> 10;
      int tap = r % 9, pc = r / 9;
      int ci = (pc >> 1) * 16 + (pc & 1) * 8 + e;
      W2b[j] = f2bf(W2[(co * 128 + ci) * 9 + tap]);
    }
  }
}

// -- NCHW fp32 -> padded plane-major bf16 [8][128][32 cig][130 px][8 ci] ----
__global__ __launch_bounds__(256) void transpose_to_bf16(
    const float* __restrict__ src, unsigned short* __restrict__ dst, int cigb) {
  int row = blockIdx.x;  // b*128+y
  int b = row >> 7, y = row & 127;
  const float* s = src + (long)b * 128 * 16384 + (long)y * 128;
  for (int it = 0; it < 8; ++it) {
    int u = it * 256 + (int)threadIdx.x;
    int cig = u >> 7, px = u & 127;
    unsigned short pk[8];
#pragma unroll
    for (int e = 0; e < 8; ++e)
      pk[e] = f2bf(s[(long)(cig * 8 + e) * 16384 + px]);
    uint4 vv;
    vv.x = (unsigned)pk[0] | ((unsigned)pk[1] << 16);
    vv.y = (unsigned)pk[2] | ((unsigned)pk[3] << 16);
    vv.z = (unsigned)pk[4] | ((unsigned)pk[5] << 16);
    vv.w = (unsigned)pk[6] | ((unsigned)pk[7] << 16);
    *(uint4*)(&dst[(((long)row * 32 + cigb + cig) * 130 + px + 1) * 8]) = vv;
  }
  if (cigb == 0 && threadIdx.x < 64) {  // zero px 0,129 for all 32 cig
    int g = threadIdx.x >> 1;
    long col = (threadIdx.x & 1) * 129L;
    *(uint4*)(&dst[(((long)row * 32 + g) * 130 + col) * 8]) = make_uint4(0, 0, 0, 0);
  }
}

// ---------------- 3x3 SAME conv, implicit GEMM, bf16 MFMA -----------------
// block = 1 image row: 128 px x 128 co, 4 waves (wco 2 x wpx 2), 256 thr.
// Weights: global->REG per wave (coalesced on the [cic][p][tap][co][8]
// layout), ky-pipelined — no weight LDS. Input: double-buffered LDS via
// global_load_lds, prefetch chunk k+1 before compute k, ONE barrier/chunk.
// FUSE_DS (conv2): 1x1 conv + entropy map + unob fused into epilogue.
template <int CIN, bool FUSE_DS>
__global__ __launch_bounds__(256, 3) void conv3x3(
    const unsigned short* __restrict__ src,  // [8][128][CIN/8][130][8]
    const unsigned short* __restrict__ wt,   // [cic][p][tap][co][8]
    const float* __restrict__ bias,          // [128]
    const unsigned short* __restrict__ zp,   // zeroed 8KB
    unsigned short* __restrict__ dst_bf16,   // [8][128][16][130][8]
    float* __restrict__ dst_f32,             // NCHW fp32 [8,128,128,128]
    const float* __restrict__ wds,           // [2,128] (FUSE_DS)
    const int* __restrict__ tar,             // [8,128,128] (FUSE_DS)
    float* __restrict__ ds,                  // [8,2,128,128] (FUSE_DS)
    float* __restrict__ amap) {              // [8,128,128] (FUSE_DS)
  constexpr int CPG = CIN / 8;
  constexpr int NC = CIN / 16;
  __shared__ unsigned short in_tile[2][6 * 130 * 8];  // [buf][seg=p*3+hy][130][8], 2x12.2KB
  __shared__ float sb[128];
  __shared__ float w0s[128], w1s[128];
  __shared__ float sc[2 * 2 * 2 * 32];

  const int tid = threadIdx.x;
  const int b = blockIdx.x >> 7;
  const int y0 = blockIdx.x & 127;
  const int lane = tid & 63, wave = tid >> 6;
  const int wco = wave & 1, wpx = wave >> 1;
  const int l31 = lane & 31, kh = lane >> 5;
  const int p0 = wpx * 64;

  if (tid < 128) {
    sb[tid] = bias[tid];
    if constexpr (FUSE_DS) {
      w0s[tid] = wds[tid];
      w1s[tid] = wds[128 + tid];
    }
  }

#define STAGE_BULK(cic, bufi)                                                  \
  {                                                                            \
    _Pragma("unroll") for (int j = 0; j < 3; ++j) {                            \
      int o = wave + j * 4;                                                    \
      int seg = o >> 1, half = o & 1;                                          \
      int p = (seg >= 3) ? 1 : 0, hy = seg - p * 3;                            \
      int gy = y0 - 1 + hy;                                                    \
      const unsigned short* g =                                                \
          (gy >= 0 && gy < 128)                                                \
              ? src + ((size_t)((b * 128 + gy) * CPG) + (cic)*2 + p) * 1040 +  \
                    (half * 64 + lane) * 8                                     \
              : zp + lane * 8;                                                 \
      gl_lds16(g, &in_tile[bufi][(size_t)(seg * 130 + half * 64) * 8]);        \
    }                                                                          \
  }

#define LOAD_TAIL(cic, v)                                                      \
  {                                                                            \
    if (tid < 12) {                                                            \
      int s_ = tid >> 1, p_ = (s_ >= 3) ? 1 : 0, hy_ = s_ - p_ * 3;            \
      int cx_ = 128 + (tid & 1);                                               \
      int gy_ = y0 - 1 + hy_;                                                  \
      if (gy_ >= 0 && gy_ < 128)                                               \
        v = *(const uint4*)(src +                                              \
                            ((size_t)((b * 128 + gy_) * CPG) + (cic)*2 + p_) * \
                                1040 +                                         \
                            cx_ * 8);                                          \
    }                                                                          \
  }

#define WRITE_TAIL(bufi, v)                                                    \
  {                                                                            \
    if (tid < 12) {                                                            \
      int s_ = tid >> 1, cx_ = 128 + (tid & 1);                                \
      *(uint4*)(&in_tile[bufi][(size_t)(s_ * 130 + cx_) * 8]) = v;             \
    }                                                                          \
  }

  f32x16 acc[2][2] = {};

  // prologue: stage chunk 0 into buf 0
  {
    uint4 tv = make_uint4(0, 0, 0, 0);
    LOAD_TAIL(0, tv);
    STAGE_BULK(0, 0);
    WRITE_TAIL(0, tv);
  }
  __syncthreads();

  // per-lane weight base. Within a chunk the plane (kh) stride is
  // 9 taps * 128 co * 8 = 9216 shorts; chunk stride 18432. (R7 bug: used
  // kh*(CIN/2)*1152 — read past W1b for kh=1.)
  const unsigned short* wlane = wt + (size_t)kh * 9216 + (size_t)(wco * 64 + l31) * 8;

  for (int cic = 0; cic < NC; ++cic) {
    const int cur = cic & 1, nbuf = cur ^ 1;
    const bool more = (cic + 1 < NC);
    // issue next chunk's input stage (tail load first -> oldest in queue)
    uint4 tl = make_uint4(0, 0, 0, 0);
    if (more) {
      LOAD_TAIL(cic + 1, tl);
      STAGE_BULK(cic + 1, nbuf);
    }
    __builtin_amdgcn_sched_barrier(0);
    // compute current chunk; weights ky-pipelined global->reg
    const unsigned short* wl = wlane + (size_t)cic * 18432;
    const unsigned short* it = in_tile[cur];
    bf16x8 a0[3], a1[3];
#pragma unroll
    for (int t = 0; t < 3; ++t) {
      a0[t] = *(const bf16x8*)(wl + t * 1024);
      a1[t] = *(const bf16x8*)(wl + t * 1024 + 256);
    }
#pragma unroll
    for (int ky = 0; ky < 3; ++ky) {
      bf16x8 n0[3], n1[3];
      if (ky < 2) {
#pragma unroll
        for (int t = 0; t < 3; ++t) {
          n0[t] = *(const bf16x8*)(wl + (ky * 3 + 3 + t) * 1024);
          n1[t] = *(const bf16x8*)(wl + (ky * 3 + 3 + t) * 1024 + 256);
        }
      }
#pragma unroll
      for (int kx = 0; kx < 3; ++kx) {
        bf16x8 b0 = *(const bf16x8*)(&it[(size_t)(kh * 390 + ky * 130 + p0 + l31 + kx) * 8]);
        bf16x8 b1 = *(const bf16x8*)(&it[(size_t)(kh * 390 + ky * 130 + p0 + 32 + l31 + kx) * 8]);
        acc[0][0] = __builtin_amdgcn_mfma_f32_32x32x16_bf16(a0[kx], b0, acc[0][0], 0, 0, 0);
        acc[0][1] = __builtin_amdgcn_mfma_f32_32x32x16_bf16(a0[kx], b1, acc[0][1], 0, 0, 0);
        acc[1][0] = __builtin_amdgcn_mfma_f32_32x32x16_bf16(a1[kx], b0, acc[1][0], 0, 0, 0);
        acc[1][1] = __builtin_amdgcn_mfma_f32_32x32x16_bf16(a1[kx], b1, acc[1][1], 0, 0, 0);
      }
      if (ky < 2) {
#pragma unroll
        for (int t = 0; t < 3; ++t) { a0[t] = n0[t]; a1[t] = n1[t]; }
      }
    }
    if (more) WRITE_TAIL(nbuf, tl);
    __syncthreads();
  }

  // ---- epilogue. D: col(px)=lane&31, row(co)=(r&3)+8*(r>>2)+4*kh
  float pd[2][2] = {};  // [fp][cls] partial ds sums (FUSE_DS)
#pragma unroll
  for (int fc = 0; fc < 2; ++fc) {
#pragma unroll
    for (int fp = 0; fp < 2; ++fp) {
      const int px = p0 + fp * 32 + l31;
      if constexpr (!FUSE_DS) {
#pragma unroll
        for (int rg = 0; rg < 4; ++rg) {
          const int co0 = wco * 64 + fc * 32 + rg * 8 + kh * 4;
          unsigned short pk[4];
#pragma unroll
          for (int q = 0; q < 4; ++q) {
            float v = acc[fc][fp][rg * 4 + q] + sb[co0 + q];
            v = v > 0.f ? v : 0.01f * v;
            pk[q] = f2bf(v);
          }
          uint2 o;
          o.x = (unsigned)pk[0] | ((unsigned)pk[1] << 16);
          o.y = (unsigned)pk[2] | ((unsigned)pk[3] << 16);
          *(uint2*)(&dst_bf16[(((long)(b * 128 + y0) * 16 + (co0 >> 3)) * 130 + px + 1) * 8 +
                              kh * 4]) = o;
        }
      } else {
#pragma unroll
        for (int rg = 0; rg < 4; ++rg) {
          const int co0 = wco * 64 + fc * 32 + rg * 8 + kh * 4;
          float4 wv0 = *(const float4*)(&w0s[co0]);
          float4 wv1 = *(const float4*)(&w1s[co0]);
#pragma unroll
          for (int q = 0; q < 4; ++q) {
            float v = acc[fc][fp][rg * 4 + q] + sb[co0 + q];
            v = v > 0.f ? v : 0.01f * v;
            dst_f32[((long)(b * 128 + co0 + q) << 14) + (y0 << 7) + px] = v;
            float wq0 = (q == 0) ? wv0.x : (q == 1) ? wv0.y : (q == 2) ? wv0.z : wv0.w;
            float wq1 = (q == 0) ? wv1.x : (q == 1) ? wv1.y : (q == 2) ? wv1.z : wv1.w;
            pd[fp][0] += wq0 * v;
            pd[fp][1] += wq1 * v;
          }
        }
      }
    }
  }

  if constexpr (!FUSE_DS) {  // zero px 0,129 of this row, all 16 cig
    if (tid < 32) {
      int g = tid >> 1;
      long col = (tid & 1) * 129L;
      *(uint4*)(&dst_bf16[(((long)(b * 128 + y0) * 16 + g) * 130 + col) * 8]) =
          make_uint4(0, 0, 0, 0);
    }
  } else {
    // reduce kh (lane^32), then wco pairs via LDS scratch
#pragma unroll
    for (int fp = 0; fp < 2; ++fp)
#pragma unroll
      for (int c = 0; c < 2; ++c)
        pd[fp][c] += __shfl_xor(pd[fp][c], 32, 64);
    if (wco == 1 && kh == 0) {
#pragma unroll
      for (int fp = 0; fp < 2; ++fp)
#pragma unroll
        for (int c = 0; c < 2; ++c)
          sc[((wpx * 2 + fp) * 2 + c) * 32 + l31] = pd[fp][c];
    }
    __syncthreads();
    if (wco == 0 && kh == 0) {
      const int* tb = tar + (long)b * 16384;
#pragma unroll
      for (int fp = 0; fp < 2; ++fp) {
        const int px = p0 + fp * 32 + l31;
        float a0 = pd[fp][0] + sc[((wpx * 2 + fp) * 2 + 0) * 32 + l31];
        float a1 = pd[fp][1] + sc[((wpx * 2 + fp) * 2 + 1) * 32 + l31];
        ds[((long)b * 2) * 16384 + (y0 << 7) + px] = a0;
        ds[((long)b * 2 + 1) * 16384 + (y0 << 7) + px] = a1;
        float m = fmaxf(a0, a1);
        float e0 = expf(a0 - m), e1 = expf(a1 - m);
        float s = e0 + e1;
        float p0f = e0 / s, p1f = e1 / s;
        float ent = -(p0f * log2f(p0f + 1e-6f) + p1f * log2f(p1f + 1e-6f));
        float un = ent >= 0.001f ? 1.f : 0.f;
        float pro = 1.f;
        if (y0 > 0 && y0 < 127 && px > 0 && px < 127) {
          int c = tb[(y0 << 7) + px];
          if (c != 0) {
            int nb2 = tb[((y0 - 1) << 7) + px] + tb[((y0 + 1) << 7) + px] +
                      tb[(y0 << 7) + px - 1] + tb[(y0 << 7) + px + 1];
            if (4 * c != nb2) pro = 0.f;
          }
        }
        amap[((long)(b * 128 + y0) << 7) + px] = un * pro;
      }
    }
  }
#undef STAGE_BULK
#undef LOAD_TAIL
#undef WRITE_TAIL
}

extern "C" void kernel_launch(void* const* d_in, const int* in_sizes, int n_in,
                              void* d_out, int out_size, void* d_ws, size_t ws_size,
                              hipStream_t stream) {
  const float* x    = (const float*)d_in[0];
  const float* skip = (const float*)d_in[1];
  const int*   tar  = (const int*)d_in[2];
  const float* W1   = (const float*)d_in[3];
  const float* b1   = (const float*)d_in[4];
  const float* W2   = (const float*)d_in[5];
  const float* b2   = (const float*)d_in[6];
  const float* Wds  = (const float*)d_in[7];

  float* out_h  = (float*)d_out;            // 16777216 f32 (h, NCHW)
  float* out_ds = out_h + 16777216;         // 262144 f32
  float* out_am = out_ds + 262144;          // 131072 f32

  // ws: W1b | W2b | zp | (1MB) h1  [8][128][16][130][8] bf16 (34.1MB)
  unsigned short* W1b = (unsigned short*)d_ws;
  unsigned short* W2b = W1b + 294912;
  unsigned short* zp  = W2b + 147456;
  unsigned short* h1  = (unsigned short*)((char*)d_ws + (1u << 20));

  // h0: [8][128][32][130][8] bf16 = 68.2MB, lives in d_out (68.7MB);
  // fully dead before conv2 overwrites d_out (h/ds/amap regions).
  unsigned short* h0 = (unsigned short*)d_out;

  convert_weights<<<1729, 256, 0, stream>>>(W1, W2, W1b, W2b, zp);
  transpose_to_bf16<<<1024, 256, 0, stream>>>(x, h0, 0);
  transpose_to_bf16<<<1024, 256, 0, stream>>>(skip, h0, 16);
  conv3x3<256, false><<<1024, 256, 0, stream>>>(h0, W1b, b1, zp, h1, nullptr,
                                                nullptr, nullptr, nullptr, nullptr);
  conv3x3<128, true><<<1024, 256, 0, stream>>>(h1, W2b, b2, zp, nullptr, out_h,
                                               Wds, tar, out_ds, out_am);
}

// Round 9
// 154.870 us; speedup vs baseline: 1.2455x; 1.2455x over previous
//
#include <hip/hip_runtime.h>

typedef float f32x16 __attribute__((ext_vector_type(16)));
typedef short bf16x8 __attribute__((ext_vector_type(8)));
typedef unsigned int u32;

static __device__ __forceinline__ unsigned short f2bf(float f) {
  union { float f; unsigned int u; } v;
  v.f = f;
  return (unsigned short)((v.u + 0x7FFFu + ((v.u >> 16) & 1u)) >> 16);
}

// async 16B global->LDS (DMA). LDS dest = wave-uniform base + lane*16.
static __device__ __forceinline__ void gl_lds16(const unsigned short* g,
                                                unsigned short* l) {
  __builtin_amdgcn_global_load_lds(
      (const __attribute__((address_space(1))) u32*)g,
      (__attribute__((address_space(3))) u32*)l, 16, 0, 0);
}

#define VMCNT4 asm volatile("s_waitcnt vmcnt(4)" ::: "memory")
#define VMCNT0 asm volatile("s_waitcnt vmcnt(0)" ::: "memory")
#define LGKM0 asm volatile("s_waitcnt lgkmcnt(0)" ::: "memory")
#define BAR __builtin_amdgcn_s_barrier()
#define SCHEDB __builtin_amdgcn_sched_barrier(0)

// ---- weights: OIHW fp32 -> [cic][p][tap][co][8ci] bf16 (contiguous 36KB
// per-chunk slab, linear order == LDS layout); + zero page.
__global__ __launch_bounds__(256) void convert_weights(
    const float* __restrict__ W1, const float* __restrict__ W2,
    unsigned short* __restrict__ W1b, unsigned short* __restrict__ W2b,
    unsigned short* __restrict__ zp) {
  if (blockIdx.x == 1728) {
    uint4* z = (uint4*)zp;
    z[threadIdx.x] = make_uint4(0, 0, 0, 0);
    z[256 + threadIdx.x] = make_uint4(0, 0, 0, 0);
    return;
  }
  int i = blockIdx.x * 256 + threadIdx.x;
  if (i < 294912) {
    int e = i & 7, co = (i >> 3) & 127, r = i >> 10;  // r=(cic*2+p)*9+tap
    int tap = r % 9, pc = r / 9;
    int ci = (pc >> 1) * 16 + (pc & 1) * 8 + e;
    W1b[i] = f2bf(W1[(co * 256 + ci) * 9 + tap]);
  } else {
    int j = i - 294912;
    if (j < 147456) {
      int e = j & 7, co = (j >> 3) & 127, r = j >> 10;
      int tap = r % 9, pc = r / 9;
      int ci = (pc >> 1) * 16 + (pc & 1) * 8 + e;
      W2b[j] = f2bf(W2[(co * 128 + ci) * 9 + tap]);
    }
  }
}

// -- NCHW fp32 -> padded plane-major bf16 [8][128][32 cig][130 px][8 ci] ----
__global__ __launch_bounds__(256) void transpose_to_bf16(
    const float* __restrict__ src, unsigned short* __restrict__ dst, int cigb) {
  int row = blockIdx.x;  // b*128+y
  int b = row >> 7, y = row & 127;
  const float* s = src + (long)b * 128 * 16384 + (long)y * 128;
  for (int it = 0; it < 8; ++it) {
    int u = it * 256 + (int)threadIdx.x;
    int cig = u >> 7, px = u & 127;
    unsigned short pk[8];
#pragma unroll
    for (int e = 0; e < 8; ++e)
      pk[e] = f2bf(s[(long)(cig * 8 + e) * 16384 + px]);
    uint4 vv;
    vv.x = (unsigned)pk[0] | ((unsigned)pk[1] << 16);
    vv.y = (unsigned)pk[2] | ((unsigned)pk[3] << 16);
    vv.z = (unsigned)pk[4] | ((unsigned)pk[5] << 16);
    vv.w = (unsigned)pk[6] | ((unsigned)pk[7] << 16);
    *(uint4*)(&dst[(((long)row * 32 + cigb + cig) * 130 + px + 1) * 8]) = vv;
  }
  if (cigb == 0 && threadIdx.x < 64) {  // zero px 0,129 for all 32 cig
    int g = threadIdx.x >> 1;
    long col = (threadIdx.x & 1) * 129L;
    *(uint4*)(&dst[(((long)row * 32 + g) * 130 + col) * 8]) = make_uint4(0, 0, 0, 0);
  }
}

// ---------------- 3x3 SAME conv, implicit GEMM, bf16 MFMA -----------------
// block = 2 rows x 128 co x 256 px, 4 waves: wave (wco, wrow) computes
// 64 co x 128 px of row y0+wrow -> acc[2 fc][4 fp], 0.75 LDS-reads/MFMA.
// Weights: single-buffered LDS (36KB/chunk). Input: double-buffered LDS.
// Per chunk: {tail(k+1), wt(k), in(k+1)} -> vmcnt(4) [in(k+1) stays in
// flight across both raw barriers] -> BAR -> compute -> BAR.  (T4)
template <int CIN, bool FUSE_DS>
__global__ __launch_bounds__(256, 2) void conv3x3(
    const unsigned short* __restrict__ src,  // [8][128][CIN/8][130][8]
    const unsigned short* __restrict__ wt,   // [cic][p][tap][co][8]
    const float* __restrict__ bias,          // [128]
    const unsigned short* __restrict__ zp,   // zeroed 8KB
    unsigned short* __restrict__ dst_bf16,   // [8][128][16][130][8]
    float* __restrict__ dst_f32,             // NCHW fp32 [8,128,128,128]
    const float* __restrict__ wds,           // [2,128] (FUSE_DS)
    const int* __restrict__ tar,             // [8,128,128] (FUSE_DS)
    float* __restrict__ ds,                  // [8,2,128,128] (FUSE_DS)
    float* __restrict__ amap) {              // [8,128,128] (FUSE_DS)
  constexpr int CPG = CIN / 8;
  constexpr int NC = CIN / 16;
  __shared__ unsigned short in_tile[2][1040 * 8];  // [buf][p][4 rows][130][8], 2x16.6KB
  __shared__ unsigned short wt_tile[2304 * 8];     // [p][tap][co][8], 36.9KB
  __shared__ float sb[128];
  __shared__ float w0s[128], w1s[128];
  __shared__ float sc[2 * 4 * 2 * 32];

  const int tid = threadIdx.x;
  const int b = blockIdx.x >> 6;
  const int y0 = (blockIdx.x & 63) * 2;
  const int lane = tid & 63, wave = tid >> 6;
  const int wco = wave & 1, wrow = wave >> 1;
  const int l31 = lane & 31, kh = lane >> 5;

  if (tid < 128) {
    sb[tid] = bias[tid];
    if constexpr (FUSE_DS) {
      w0s[tid] = wds[tid];
      w1s[tid] = wds[128 + tid];
    }
  }

  // input stage: 1040 16B-slots = [p][hy(4)][hx(130)]; bulk 1024 via 16 ops
  // (4/wave, consecutive), tail = slots 1024..1039 (p1,hy3,hx114..129).
#define STAGE_IN(cic, bufi)                                                    \
  {                                                                            \
    _Pragma("unroll") for (int j = 0; j < 4; ++j) {                            \
      int o = wave * 4 + j;                                                    \
      int s = o * 64 + lane;                                                   \
      int p = s >= 520;                                                        \
      int r = s - p * 520;                                                     \
      int hy = r / 130;                                                        \
      int hx = r - hy * 130;                                                   \
      int gy = y0 - 1 + hy;                                                    \
      const unsigned short* g =                                                \
          (gy >= 0 && gy < 128)                                                \
              ? src + ((size_t)((b * 128 + gy) * CPG) + (size_t)(cic)*2 + p) * \
                          1040 +                                               \
                    hx * 8                                                     \
              : zp + lane * 8;                                                 \
      gl_lds16(g, &in_tile[bufi][(size_t)o * 512]);                            \
    }                                                                          \
  }

#define STAGE_WT(cic)                                                          \
  {                                                                            \
    const unsigned short* wslab = wt + (size_t)(cic)*18432;                    \
    _Pragma("unroll") for (int j = 0; j < 9; ++j) {                            \
      int o = wave * 9 + j;                                                    \
      gl_lds16(wslab + o * 512 + lane * 8, &wt_tile[(size_t)o * 512]);         \
    }                                                                          \
  }

#define LOAD_TAIL(cic, v)                                                      \
  {                                                                            \
    if (tid < 16) {                                                            \
      int gy_ = y0 + 2;                                                        \
      if (gy_ < 128)                                                           \
        v = *(const uint4*)(src +                                              \
                            ((size_t)((b * 128 + gy_) * CPG) +                 \
                             (size_t)(cic)*2 + 1) *                            \
                                1040 +                                         \
                            (114 + tid) * 8);                                  \
    }                                                                          \
  }

#define WRITE_TAIL(bufi, v)                                                    \
  {                                                                            \
    if (tid < 16) *(uint4*)(&in_tile[bufi][(size_t)(1024 + tid) * 8]) = v;     \
  }

  f32x16 acc[2][4] = {};

  // prologue: stage input chunk 0 into buf 0
  {
    uint4 tv = make_uint4(0, 0, 0, 0);
    LOAD_TAIL(0, tv);
    STAGE_IN(0, 0);
    VMCNT0;
    WRITE_TAIL(0, tv);
    LGKM0;
    BAR;
    SCHEDB;
  }

  for (int cic = 0; cic < NC; ++cic) {
    const int cur = cic & 1;
    const bool more = (cic + 1 < NC);
    // stage phase: tail(k+1) first (oldest), wt(k), in(k+1)
    uint4 tl = make_uint4(0, 0, 0, 0);
    if (more) LOAD_TAIL(cic + 1, tl);
    STAGE_WT(cic);
    if (more) {
      STAGE_IN(cic + 1, cur ^ 1);
      VMCNT4;  // drains tail+wt(k)+in(k); leaves in(k+1) 4 ops in flight
      SCHEDB;
      WRITE_TAIL(cur ^ 1, tl);
    } else {
      VMCNT0;
      SCHEDB;
    }
    LGKM0;
    BAR;  // B1: all waves' wt(k) + in(k) landed
    SCHEDB;

    // compute chunk k
    const unsigned short* it = in_tile[cur];
    const size_t wb = (size_t)kh * 9216;  // plane base in wt_tile (shorts)
    const size_t ib = (size_t)kh * 4160;  // plane base in in_tile (shorts)
#pragma unroll
    for (int ky = 0; ky < 3; ++ky) {
      const int hy = ky + wrow;
#pragma unroll
      for (int kx = 0; kx < 3; ++kx) {
        const int t = ky * 3 + kx;
        bf16x8 a0 = *(const bf16x8*)(&wt_tile[wb + (size_t)(t * 128 + wco * 64 + l31) * 8]);
        bf16x8 a1 = *(const bf16x8*)(&wt_tile[wb + (size_t)(t * 128 + wco * 64 + 32 + l31) * 8]);
        bf16x8 b0 = *(const bf16x8*)(&it[ib + (size_t)(hy * 130 + l31 + kx) * 8]);
        bf16x8 b1 = *(const bf16x8*)(&it[ib + (size_t)(hy * 130 + 32 + l31 + kx) * 8]);
        bf16x8 b2 = *(const bf16x8*)(&it[ib + (size_t)(hy * 130 + 64 + l31 + kx) * 8]);
        bf16x8 b3 = *(const bf16x8*)(&it[ib + (size_t)(hy * 130 + 96 + l31 + kx) * 8]);
        acc[0][0] = __builtin_amdgcn_mfma_f32_32x32x16_bf16(a0, b0, acc[0][0], 0, 0, 0);
        acc[0][1] = __builtin_amdgcn_mfma_f32_32x32x16_bf16(a0, b1, acc[0][1], 0, 0, 0);
        acc[0][2] = __builtin_amdgcn_mfma_f32_32x32x16_bf16(a0, b2, acc[0][2], 0, 0, 0);
        acc[0][3] = __builtin_amdgcn_mfma_f32_32x32x16_bf16(a0, b3, acc[0][3], 0, 0, 0);
        acc[1][0] = __builtin_amdgcn_mfma_f32_32x32x16_bf16(a1, b0, acc[1][0], 0, 0, 0);
        acc[1][1] = __builtin_amdgcn_mfma_f32_32x32x16_bf16(a1, b1, acc[1][1], 0, 0, 0);
        acc[1][2] = __builtin_amdgcn_mfma_f32_32x32x16_bf16(a1, b2, acc[1][2], 0, 0, 0);
        acc[1][3] = __builtin_amdgcn_mfma_f32_32x32x16_bf16(a1, b3, acc[1][3], 0, 0, 0);
      }
    }
    SCHEDB;
    LGKM0;  // my ds_reads retired
    BAR;    // B2: safe to overwrite wt_tile / stage into in_tile[cur] next iter
    SCHEDB;
  }

  // ---- epilogue. D: col(px)=lane&31, row(co)=(r&3)+8*(r>>2)+4*kh
  const int gyo = y0 + wrow;
  float pd[4][2] = {};  // [fp][cls] (FUSE_DS)
#pragma unroll
  for (int fc = 0; fc < 2; ++fc) {
#pragma unroll
    for (int fp = 0; fp < 4; ++fp) {
      const int px = fp * 32 + l31;
      if constexpr (!FUSE_DS) {
#pragma unroll
        for (int rg = 0; rg < 4; ++rg) {
          const int co0 = wco * 64 + fc * 32 + rg * 8 + kh * 4;
          unsigned short pk[4];
#pragma unroll
          for (int q = 0; q < 4; ++q) {
            float v = acc[fc][fp][rg * 4 + q] + sb[co0 + q];
            v = v > 0.f ? v : 0.01f * v;
            pk[q] = f2bf(v);
          }
          uint2 o;
          o.x = (unsigned)pk[0] | ((unsigned)pk[1] << 16);
          o.y = (unsigned)pk[2] | ((unsigned)pk[3] << 16);
          *(uint2*)(&dst_bf16[(((long)(b * 128 + gyo) * 16 + (co0 >> 3)) * 130 + px + 1) * 8 +
                              kh * 4]) = o;
        }
      } else {
#pragma unroll
        for (int rg = 0; rg < 4; ++rg) {
          const int co0 = wco * 64 + fc * 32 + rg * 8 + kh * 4;
          float4 wv0 = *(const float4*)(&w0s[co0]);
          float4 wv1 = *(const float4*)(&w1s[co0]);
#pragma unroll
          for (int q = 0; q < 4; ++q) {
            float v = acc[fc][fp][rg * 4 + q] + sb[co0 + q];
            v = v > 0.f ? v : 0.01f * v;
            dst_f32[((long)(b * 128 + co0 + q) << 14) + (gyo << 7) + px] = v;
            float wq0 = (q == 0) ? wv0.x : (q == 1) ? wv0.y : (q == 2) ? wv0.z : wv0.w;
            float wq1 = (q == 0) ? wv1.x : (q == 1) ? wv1.y : (q == 2) ? wv1.z : wv1.w;
            pd[fp][0] += wq0 * v;
            pd[fp][1] += wq1 * v;
          }
        }
      }
    }
  }

  if constexpr (!FUSE_DS) {  // zero px 0,129 of this block's 2 rows, all cig
    if (tid < 64) {
      int row = tid >> 5, g = (tid >> 1) & 15;
      long col = (tid & 1) * 129L;
      *(uint4*)(&dst_bf16[(((long)(b * 128 + y0 + row) * 16 + g) * 130 + col) * 8]) =
          make_uint4(0, 0, 0, 0);
    }
  } else {
    // reduce kh (lane^32), then wco pairs via LDS scratch
#pragma unroll
    for (int fp = 0; fp < 4; ++fp)
#pragma unroll
      for (int c = 0; c < 2; ++c)
        pd[fp][c] += __shfl_xor(pd[fp][c], 32, 64);
    if (wco == 1 && kh == 0) {
#pragma unroll
      for (int fp = 0; fp < 4; ++fp)
#pragma unroll
        for (int c = 0; c < 2; ++c)
          sc[((wrow * 4 + fp) * 2 + c) * 32 + l31] = pd[fp][c];
    }
    __syncthreads();
    if (wco == 0 && kh == 0) {
      const int* tb = tar + (long)b * 16384;
#pragma unroll
      for (int fp = 0; fp < 4; ++fp) {
        const int px = fp * 32 + l31;
        float a0 = pd[fp][0] + sc[((wrow * 4 + fp) * 2 + 0) * 32 + l31];
        float a1 = pd[fp][1] + sc[((wrow * 4 + fp) * 2 + 1) * 32 + l31];
        ds[((long)b * 2) * 16384 + (gyo << 7) + px] = a0;
        ds[((long)b * 2 + 1) * 16384 + (gyo << 7) + px] = a1;
        float m = fmaxf(a0, a1);
        float e0 = expf(a0 - m), e1 = expf(a1 - m);
        float s = e0 + e1;
        float p0f = e0 / s, p1f = e1 / s;
        float ent = -(p0f * log2f(p0f + 1e-6f) + p1f * log2f(p1f + 1e-6f));
        float un = ent >= 0.001f ? 1.f : 0.f;
        float pro = 1.f;
        if (gyo > 0 && gyo < 127 && px > 0 && px < 127) {
          int c = tb[(gyo << 7) + px];
          if (c != 0) {
            int nb2 = tb[((gyo - 1) << 7) + px] + tb[((gyo + 1) << 7) + px] +
                      tb[(gyo << 7) + px - 1] + tb[(gyo << 7) + px + 1];
            if (4 * c != nb2) pro = 0.f;
          }
        }
        amap[((long)(b * 128 + gyo) << 7) + px] = un * pro;
      }
    }
  }
#undef STAGE_IN
#undef STAGE_WT
#undef LOAD_TAIL
#undef WRITE_TAIL
}

extern "C" void kernel_launch(void* const* d_in, const int* in_sizes, int n_in,
                              void* d_out, int out_size, void* d_ws, size_t ws_size,
                              hipStream_t stream) {
  const float* x    = (const float*)d_in[0];
  const float* skip = (const float*)d_in[1];
  const int*   tar  = (const int*)d_in[2];
  const float* W1   = (const float*)d_in[3];
  const float* b1   = (const float*)d_in[4];
  const float* W2   = (const float*)d_in[5];
  const float* b2   = (const float*)d_in[6];
  const float* Wds  = (const float*)d_in[7];

  float* out_h  = (float*)d_out;            // 16777216 f32 (h, NCHW)
  float* out_ds = out_h + 16777216;         // 262144 f32
  float* out_am = out_ds + 262144;          // 131072 f32

  // ws: W1b | W2b | zp | (1MB) h1  [8][128][16][130][8] bf16 (34.1MB)
  unsigned short* W1b = (unsigned short*)d_ws;
  unsigned short* W2b = W1b + 294912;
  unsigned short* zp  = W2b + 147456;
  unsigned short* h1  = (unsigned short*)((char*)d_ws + (1u << 20));

  // h0: [8][128][32][130][8] bf16 = 68.2MB, lives in d_out (68.7MB);
  // fully dead before conv2 overwrites d_out (h/ds/amap regions).
  unsigned short* h0 = (unsigned short*)d_out;

  convert_weights<<<1729, 256, 0, stream>>>(W1, W2, W1b, W2b, zp);
  transpose_to_bf16<<<1024, 256, 0, stream>>>(x, h0, 0);
  transpose_to_bf16<<<1024, 256, 0, stream>>>(skip, h0, 16);
  conv3x3<256, false><<<512, 256, 0, stream>>>(h0, W1b, b1, zp, h1, nullptr,
                                               nullptr, nullptr, nullptr, nullptr);
  conv3x3<128, true><<<512, 256, 0, stream>>>(h1, W2b, b2, zp, nullptr, out_h,
                                              Wds, tar, out_ds, out_am);
}

// Round 10
// 150.365 us; speedup vs baseline: 1.2829x; 1.0300x over previous
//
#include <hip/hip_runtime.h>

typedef float f32x16 __attribute__((ext_vector_type(16)));
typedef short bf16x8 __attribute__((ext_vector_type(8)));
typedef unsigned int u32;

static __device__ __forceinline__ unsigned short f2bf(float f) {
  union { float f; unsigned int u; } v;
  v.f = f;
  return (unsigned short)((v.u + 0x7FFFu + ((v.u >> 16) & 1u)) >> 16);
}

// async 16B global->LDS (DMA). LDS dest = wave-uniform base + lane*16.
static __device__ __forceinline__ void gl_lds16(const unsigned short* g,
                                                unsigned short* l) {
  __builtin_amdgcn_global_load_lds(
      (const __attribute__((address_space(1))) u32*)g,
      (__attribute__((address_space(3))) u32*)l, 16, 0, 0);
}

#define VMCNT8 asm volatile("s_waitcnt vmcnt(8)" ::: "memory")
#define VMCNT0 asm volatile("s_waitcnt vmcnt(0)" ::: "memory")
#define LGKM0 asm volatile("s_waitcnt lgkmcnt(0)" ::: "memory")
#define BAR __builtin_amdgcn_s_barrier()
#define SCHEDB __builtin_amdgcn_sched_barrier(0)

// ---- weights: OIHW fp32 -> [cic][p][tap][co][8ci] bf16 (contiguous 36KB
// per-chunk slab, linear order == LDS layout); + zero page.
__global__ __launch_bounds__(256) void convert_weights(
    const float* __restrict__ W1, const float* __restrict__ W2,
    unsigned short* __restrict__ W1b, unsigned short* __restrict__ W2b,
    unsigned short* __restrict__ zp) {
  if (blockIdx.x == 1728) {
    uint4* z = (uint4*)zp;
    z[threadIdx.x] = make_uint4(0, 0, 0, 0);
    z[256 + threadIdx.x] = make_uint4(0, 0, 0, 0);
    return;
  }
  int i = blockIdx.x * 256 + threadIdx.x;
  if (i < 294912) {
    int e = i & 7, co = (i >> 3) & 127, r = i >> 10;  // r=(cic*2+p)*9+tap
    int tap = r % 9, pc = r / 9;
    int ci = (pc >> 1) * 16 + (pc & 1) * 8 + e;
    W1b[i] = f2bf(W1[(co * 256 + ci) * 9 + tap]);
  } else {
    int j = i - 294912;
    if (j < 147456) {
      int e = j & 7, co = (j >> 3) & 127, r = j >> 10;
      int tap = r % 9, pc = r / 9;
      int ci = (pc >> 1) * 16 + (pc & 1) * 8 + e;
      W2b[j] = f2bf(W2[(co * 128 + ci) * 9 + tap]);
    }
  }
}

// -- NCHW fp32 -> padded plane-major bf16 [8][128][32 cig][130 px][8 ci] ----
__global__ __launch_bounds__(256) void transpose_to_bf16(
    const float* __restrict__ src, unsigned short* __restrict__ dst, int cigb) {
  int row = blockIdx.x;  // b*128+y
  int b = row >> 7, y = row & 127;
  const float* s = src + (long)b * 128 * 16384 + (long)y * 128;
  for (int it = 0; it < 8; ++it) {
    int u = it * 256 + (int)threadIdx.x;
    int cig = u >> 7, px = u & 127;
    unsigned short pk[8];
#pragma unroll
    for (int e = 0; e < 8; ++e)
      pk[e] = f2bf(s[(long)(cig * 8 + e) * 16384 + px]);
    uint4 vv;
    vv.x = (unsigned)pk[0] | ((unsigned)pk[1] << 16);
    vv.y = (unsigned)pk[2] | ((unsigned)pk[3] << 16);
    vv.z = (unsigned)pk[4] | ((unsigned)pk[5] << 16);
    vv.w = (unsigned)pk[6] | ((unsigned)pk[7] << 16);
    *(uint4*)(&dst[(((long)row * 32 + cigb + cig) * 130 + px + 1) * 8]) = vv;
  }
  if (cigb == 0 && threadIdx.x < 64) {  // zero px 0,129 for all 32 cig
    int g = threadIdx.x >> 1;
    long col = (threadIdx.x & 1) * 129L;
    *(uint4*)(&dst[(((long)row * 32 + g) * 130 + col) * 8]) = make_uint4(0, 0, 0, 0);
  }
}

// ---------------- 3x3 SAME conv, implicit GEMM, bf16 MFMA -----------------
// block = 4 rows x 128 co x 128 px, 8 waves (wco 2 x wrow 4), 512 thr.
// FULLY double-buffered (input AND weights). Per chunk, each wave issues
// EXACTLY 8 gl_lds ops for chunk k+1 (flat 64-op table: 36 wt + 26 in +
// 2 dummy), then vmcnt(8) -> barrier -> compute(k) -> lgkmcnt(0) -> barrier.
// Steady state: chunk-k ops had all of compute(k-1) to land -> no drain.
// FUSE_DS (conv2): 1x1 conv to 2 classes + entropy + unob in epilogue.
template <int CIN, bool FUSE_DS>
__global__ __launch_bounds__(512, 2) void conv3x3(
    const unsigned short* __restrict__ src,  // [8][128][CIN/8][130][8]
    const unsigned short* __restrict__ wt,   // [cic][p][tap][co][8]
    const float* __restrict__ bias,          // [128]
    const unsigned short* __restrict__ zp,   // zeroed 8KB
    unsigned short* __restrict__ dst_bf16,   // [8][128][16][130][8]
    float* __restrict__ dst_f32,             // NCHW fp32 [8,128,128,128]
    const float* __restrict__ wds,           // [2,128] (FUSE_DS)
    const int* __restrict__ tar,             // [8,128,128] (FUSE_DS)
    float* __restrict__ ds,                  // [8,2,128,128] (FUSE_DS)
    float* __restrict__ amap) {              // [8,128,128] (FUSE_DS)
  constexpr int CPG = CIN / 8;
  constexpr int NC = CIN / 16;
  // input plane padded to 832 slots (13 ops x 64); 6 halo rows x 130 used.
  __shared__ unsigned short in_tile[2][1664 * 8];  // 2 x 26 KB
  __shared__ unsigned short wt_tile[2][2304 * 8];  // 2 x 36.9 KB
  __shared__ unsigned short scr[64 * 8];           // dummy-op sink, 1 KB
  __shared__ float sb[128];
  __shared__ float w0s[128], w1s[128];
  __shared__ float sc[4 * 4 * 2 * 32];

  const int tid = threadIdx.x;
  const int b = blockIdx.x >> 5;
  const int y0 = (blockIdx.x & 31) * 4;
  const int lane = tid & 63, wave = tid >> 6;
  const int wco = wave & 1, wrow = wave >> 1;
  const int l31 = lane & 31, kh = lane >> 5;

  if (tid < 128) {
    sb[tid] = bias[tid];
    if constexpr (FUSE_DS) {
      w0s[tid] = wds[tid];
      w1s[tid] = wds[128 + tid];
    }
  }

  // ---- flat op table: ops 0..35 = wt slab, 36..61 = input, 62..63 dummy
  const unsigned short* gb[8];  // per-op global base (this lane)
  unsigned short* ld0[8];       // per-op LDS dest (buf 0)
  int gst[8];                   // per-op global chunk stride (shorts)
  int lst[8];                   // per-op LDS buf stride (shorts)
#pragma unroll
  for (int i = 0; i < 8; ++i) {
    const int o = wave * 8 + i;
    if (o < 36) {
      gb[i] = wt + o * 512 + lane * 8;
      gst[i] = 18432;
      ld0[i] = &wt_tile[0][(size_t)o * 512];
      lst[i] = 18432;
    } else if (o < 62) {
      const int q = o - 36;
      const int p = q / 13, j = q - p * 13;
      const int s = j * 64 + lane;
      const int hy = s / 130, hx = s - hy * 130;
      const int gy = y0 - 1 + hy;
      const bool ok = (s < 780) && (gy >= 0) && (gy < 128);
      gb[i] = ok ? src + ((size_t)((b * 128 + gy) * CPG) + p) * 1040 + hx * 8
                 : zp + lane * 8;
      gst[i] = ok ? 2080 : 0;
      ld0[i] = &in_tile[0][(size_t)(p * 832 + j * 64) * 8];
      lst[i] = 1664 * 8;
    } else {
      gb[i] = zp + lane * 8;
      gst[i] = 0;
      ld0[i] = &scr[0];
      lst[i] = 0;
    }
  }

  f32x16 acc[2][4] = {};

  // prologue: stage chunk 0 into buf 0
#pragma unroll
  for (int i = 0; i < 8; ++i) gl_lds16(gb[i], ld0[i]);
  VMCNT0;
  LGKM0;
  BAR;
  SCHEDB;

  for (int cic = 0; cic < NC; ++cic) {
    const int cur = cic & 1;
    const bool more = (cic + 1 < NC);
    if (more) {
      const int nb = cur ^ 1;
#pragma unroll
      for (int i = 0; i < 8; ++i)
        gl_lds16(gb[i] + (size_t)(cic + 1) * gst[i],
                 ld0[i] + (size_t)nb * lst[i]);
      SCHEDB;
      VMCNT8;  // waits only for chunk-k ops (issued last iter, already landed)
    } else {
      VMCNT0;
    }
    SCHEDB;
    BAR;  // B1: chunk k fully staged for all waves
    SCHEDB;

    // compute chunk k
    const unsigned short* it = &in_tile[cur][0];
    const unsigned short* wl = &wt_tile[cur][0];
    const size_t ib = (size_t)kh * (832 * 8);
    const size_t wb = (size_t)kh * 9216;
#pragma unroll
    for (int ky = 0; ky < 3; ++ky) {
      const int hy = ky + wrow;
#pragma unroll
      for (int kx = 0; kx < 3; ++kx) {
        const int t = ky * 3 + kx;
        bf16x8 a0 = *(const bf16x8*)(&wl[wb + (size_t)(t * 128 + wco * 64 + l31) * 8]);
        bf16x8 a1 = *(const bf16x8*)(&wl[wb + (size_t)(t * 128 + wco * 64 + 32 + l31) * 8]);
        bf16x8 b0 = *(const bf16x8*)(&it[ib + (size_t)(hy * 130 + l31 + kx) * 8]);
        bf16x8 b1 = *(const bf16x8*)(&it[ib + (size_t)(hy * 130 + 32 + l31 + kx) * 8]);
        bf16x8 b2 = *(const bf16x8*)(&it[ib + (size_t)(hy * 130 + 64 + l31 + kx) * 8]);
        bf16x8 b3 = *(const bf16x8*)(&it[ib + (size_t)(hy * 130 + 96 + l31 + kx) * 8]);
        acc[0][0] = __builtin_amdgcn_mfma_f32_32x32x16_bf16(a0, b0, acc[0][0], 0, 0, 0);
        acc[0][1] = __builtin_amdgcn_mfma_f32_32x32x16_bf16(a0, b1, acc[0][1], 0, 0, 0);
        acc[0][2] = __builtin_amdgcn_mfma_f32_32x32x16_bf16(a0, b2, acc[0][2], 0, 0, 0);
        acc[0][3] = __builtin_amdgcn_mfma_f32_32x32x16_bf16(a0, b3, acc[0][3], 0, 0, 0);
        acc[1][0] = __builtin_amdgcn_mfma_f32_32x32x16_bf16(a1, b0, acc[1][0], 0, 0, 0);
        acc[1][1] = __builtin_amdgcn_mfma_f32_32x32x16_bf16(a1, b1, acc[1][1], 0, 0, 0);
        acc[1][2] = __builtin_amdgcn_mfma_f32_32x32x16_bf16(a1, b2, acc[1][2], 0, 0, 0);
        acc[1][3] = __builtin_amdgcn_mfma_f32_32x32x16_bf16(a1, b3, acc[1][3], 0, 0, 0);
      }
    }
    SCHEDB;
    LGKM0;  // my ds_reads retired
    BAR;    // B2: buffers safe to overwrite next iteration
    SCHEDB;
  }

  // ---- epilogue. D: col(px)=lane&31, row(co)=(r&3)+8*(r>>2)+4*kh
  const int gyo = y0 + wrow;
  float pd[4][2] = {};  // [fp][cls] (FUSE_DS)
#pragma unroll
  for (int fc = 0; fc < 2; ++fc) {
#pragma unroll
    for (int fp = 0; fp < 4; ++fp) {
      const int px = fp * 32 + l31;
      if constexpr (!FUSE_DS) {
#pragma unroll
        for (int rg = 0; rg < 4; ++rg) {
          const int co0 = wco * 64 + fc * 32 + rg * 8 + kh * 4;
          unsigned short pk[4];
#pragma unroll
          for (int q = 0; q < 4; ++q) {
            float v = acc[fc][fp][rg * 4 + q] + sb[co0 + q];
            v = v > 0.f ? v : 0.01f * v;
            pk[q] = f2bf(v);
          }
          uint2 o;
          o.x = (unsigned)pk[0] | ((unsigned)pk[1] << 16);
          o.y = (unsigned)pk[2] | ((unsigned)pk[3] << 16);
          *(uint2*)(&dst_bf16[(((long)(b * 128 + gyo) * 16 + (co0 >> 3)) * 130 + px + 1) * 8 +
                              kh * 4]) = o;
        }
      } else {
#pragma unroll
        for (int rg = 0; rg < 4; ++rg) {
          const int co0 = wco * 64 + fc * 32 + rg * 8 + kh * 4;
          float4 wv0 = *(const float4*)(&w0s[co0]);
          float4 wv1 = *(const float4*)(&w1s[co0]);
#pragma unroll
          for (int q = 0; q < 4; ++q) {
            float v = acc[fc][fp][rg * 4 + q] + sb[co0 + q];
            v = v > 0.f ? v : 0.01f * v;
            dst_f32[((long)(b * 128 + co0 + q) << 14) + (gyo << 7) + px] = v;
            float wq0 = (q == 0) ? wv0.x : (q == 1) ? wv0.y : (q == 2) ? wv0.z : wv0.w;
            float wq1 = (q == 0) ? wv1.x : (q == 1) ? wv1.y : (q == 2) ? wv1.z : wv1.w;
            pd[fp][0] += wq0 * v;
            pd[fp][1] += wq1 * v;
          }
        }
      }
    }
  }

  if constexpr (!FUSE_DS) {  // zero px 0,129 of this block's 4 rows, all cig
    if (tid < 128) {
      int row = tid >> 5, g = (tid >> 1) & 15;
      long col = (tid & 1) * 129L;
      *(uint4*)(&dst_bf16[(((long)(b * 128 + y0 + row) * 16 + g) * 130 + col) * 8]) =
          make_uint4(0, 0, 0, 0);
    }
  } else {
    // reduce kh (lane^32), then wco pairs via LDS scratch
#pragma unroll
    for (int fp = 0; fp < 4; ++fp)
#pragma unroll
      for (int c = 0; c < 2; ++c)
        pd[fp][c] += __shfl_xor(pd[fp][c], 32, 64);
    if (wco == 1 && kh == 0) {
#pragma unroll
      for (int fp = 0; fp < 4; ++fp)
#pragma unroll
        for (int c = 0; c < 2; ++c)
          sc[((wrow * 4 + fp) * 2 + c) * 32 + l31] = pd[fp][c];
    }
    __syncthreads();
    if (wco == 0 && kh == 0) {
      const int* tb = tar + (long)b * 16384;
#pragma unroll
      for (int fp = 0; fp < 4; ++fp) {
        const int px = fp * 32 + l31;
        float a0 = pd[fp][0] + sc[((wrow * 4 + fp) * 2 + 0) * 32 + l31];
        float a1 = pd[fp][1] + sc[((wrow * 4 + fp) * 2 + 1) * 32 + l31];
        ds[((long)b * 2) * 16384 + (gyo << 7) + px] = a0;
        ds[((long)b * 2 + 1) * 16384 + (gyo << 7) + px] = a1;
        float m = fmaxf(a0, a1);
        float e0 = expf(a0 - m), e1 = expf(a1 - m);
        float s = e0 + e1;
        float p0f = e0 / s, p1f = e1 / s;
        float ent = -(p0f * log2f(p0f + 1e-6f) + p1f * log2f(p1f + 1e-6f));
        float un = ent >= 0.001f ? 1.f : 0.f;
        float pro = 1.f;
        if (gyo > 0 && gyo < 127 && px > 0 && px < 127) {
          int c = tb[(gyo << 7) + px];
          if (c != 0) {
            int nb2 = tb[((gyo - 1) << 7) + px] + tb[((gyo + 1) << 7) + px] +
                      tb[(gyo << 7) + px - 1] + tb[(gyo << 7) + px + 1];
            if (4 * c != nb2) pro = 0.f;
          }
        }
        amap[((long)(b * 128 + gyo) << 7) + px] = un * pro;
      }
    }
  }
}

extern "C" void kernel_launch(void* const* d_in, const int* in_sizes, int n_in,
                              void* d_out, int out_size, void* d_ws, size_t ws_size,
                              hipStream_t stream) {
  const float* x    = (const float*)d_in[0];
  const float* skip = (const float*)d_in[1];
  const int*   tar  = (const int*)d_in[2];
  const float* W1   = (const float*)d_in[3];
  const float* b1   = (const float*)d_in[4];
  const float* W2   = (const float*)d_in[5];
  const float* b2   = (const float*)d_in[6];
  const float* Wds  = (const float*)d_in[7];

  float* out_h  = (float*)d_out;            // 16777216 f32 (h, NCHW)
  float* out_ds = out_h + 16777216;         // 262144 f32
  float* out_am = out_ds + 262144;          // 131072 f32

  // ws: W1b | W2b | zp | (1MB) h1  [8][128][16][130][8] bf16 (34.1MB)
  unsigned short* W1b = (unsigned short*)d_ws;
  unsigned short* W2b = W1b + 294912;
  unsigned short* zp  = W2b + 147456;
  unsigned short* h1  = (unsigned short*)((char*)d_ws + (1u << 20));

  // h0: [8][128][32][130][8] bf16 = 68.2MB, lives in d_out (68.7MB);
  // fully dead before conv2 overwrites d_out (h/ds/amap regions).
  unsigned short* h0 = (unsigned short*)d_out;

  convert_weights<<<1729, 256, 0, stream>>>(W1, W2, W1b, W2b, zp);
  transpose_to_bf16<<<1024, 256, 0, stream>>>(x, h0, 0);
  transpose_to_bf16<<<1024, 256, 0, stream>>>(skip, h0, 16);
  conv3x3<256, false><<<256, 512, 0, stream>>>(h0, W1b, b1, zp, h1, nullptr,
                                               nullptr, nullptr, nullptr, nullptr);
  conv3x3<128, true><<<256, 512, 0, stream>>>(h1, W2b, b2, zp, nullptr, out_h,
                                              Wds, tar, out_ds, out_am);
}

// Round 11
// 149.306 us; speedup vs baseline: 1.2920x; 1.0071x over previous
//
#include <hip/hip_runtime.h>

typedef float f32x16 __attribute__((ext_vector_type(16)));
typedef short bf16x8 __attribute__((ext_vector_type(8)));
typedef unsigned int u32;

static __device__ __forceinline__ unsigned short f2bf(float f) {
  union { float f; unsigned int u; } v;
  v.f = f;
  return (unsigned short)((v.u + 0x7FFFu + ((v.u >> 16) & 1u)) >> 16);
}

// async 16B global->LDS (DMA). LDS dest = wave-uniform base + lane*16.
static __device__ __forceinline__ void gl_lds16(const unsigned short* g,
                                                unsigned short* l) {
  __builtin_amdgcn_global_load_lds(
      (const __attribute__((address_space(1))) u32*)g,
      (__attribute__((address_space(3))) u32*)l, 16, 0, 0);
}

#define VMCNT8 asm volatile("s_waitcnt vmcnt(8)" ::: "memory")
#define VMCNT0 asm volatile("s_waitcnt vmcnt(0)" ::: "memory")
#define LGKM0 asm volatile("s_waitcnt lgkmcnt(0)" ::: "memory")
#define BAR __builtin_amdgcn_s_barrier()
#define SCHEDB __builtin_amdgcn_sched_barrier(0)
#define PRIO1 __builtin_amdgcn_s_setprio(1)
#define PRIO0 __builtin_amdgcn_s_setprio(0)

// ---- weights: OIHW fp32 -> [cic][p][tap][co][8ci] bf16 (contiguous 36KB
// per-chunk slab, linear order == LDS layout); + zero page.
__global__ __launch_bounds__(256) void convert_weights(
    const float* __restrict__ W1, const float* __restrict__ W2,
    unsigned short* __restrict__ W1b, unsigned short* __restrict__ W2b,
    unsigned short* __restrict__ zp) {
  if (blockIdx.x == 1728) {
    uint4* z = (uint4*)zp;
    z[threadIdx.x] = make_uint4(0, 0, 0, 0);
    z[256 + threadIdx.x] = make_uint4(0, 0, 0, 0);
    return;
  }
  int i = blockIdx.x * 256 + threadIdx.x;
  if (i < 294912) {
    int e = i & 7, co = (i >> 3) & 127, r = i >> 10;  // r=(cic*2+p)*9+tap
    int tap = r % 9, pc = r / 9;
    int ci = (pc >> 1) * 16 + (pc & 1) * 8 + e;
    W1b[i] = f2bf(W1[(co * 256 + ci) * 9 + tap]);
  } else {
    int j = i - 294912;
    if (j < 147456) {
      int e = j & 7, co = (j >> 3) & 127, r = j >> 10;
      int tap = r % 9, pc = r / 9;
      int ci = (pc >> 1) * 16 + (pc & 1) * 8 + e;
      W2b[j] = f2bf(W2[(co * 128 + ci) * 9 + tap]);
    }
  }
}

// -- NCHW fp32 -> padded plane-major bf16 [8][128][32 cig][130 px][8 ci] ----
__global__ __launch_bounds__(256) void transpose_to_bf16(
    const float* __restrict__ src, unsigned short* __restrict__ dst, int cigb) {
  int row = blockIdx.x;  // b*128+y
  int b = row >> 7, y = row & 127;
  const float* s = src + (long)b * 128 * 16384 + (long)y * 128;
  for (int it = 0; it < 8; ++it) {
    int u = it * 256 + (int)threadIdx.x;
    int cig = u >> 7, px = u & 127;
    unsigned short pk[8];
#pragma unroll
    for (int e = 0; e < 8; ++e)
      pk[e] = f2bf(s[(long)(cig * 8 + e) * 16384 + px]);
    uint4 vv;
    vv.x = (unsigned)pk[0] | ((unsigned)pk[1] << 16);
    vv.y = (unsigned)pk[2] | ((unsigned)pk[3] << 16);
    vv.z = (unsigned)pk[4] | ((unsigned)pk[5] << 16);
    vv.w = (unsigned)pk[6] | ((unsigned)pk[7] << 16);
    *(uint4*)(&dst[(((long)row * 32 + cigb + cig) * 130 + px + 1) * 8]) = vv;
  }
  if (cigb == 0 && threadIdx.x < 64) {  // zero px 0,129 for all 32 cig
    int g = threadIdx.x >> 1;
    long col = (threadIdx.x & 1) * 129L;
    *(uint4*)(&dst[(((long)row * 32 + g) * 130 + col) * 8]) = make_uint4(0, 0, 0, 0);
  }
}

// ---------------- 3x3 SAME conv, implicit GEMM, bf16 MFMA -----------------
// block = 4 rows x 128 co x 128 px, 8 waves (wco 2 x wrow 4), 512 thr.
// Fully double-buffered staging (R10, unchanged). NEW: compute cluster is a
// 2-deep tap software pipeline — LD(t+1) issued before MFMA(t) with
// sched_barrier pinning, so each wave keeps 6 ds_reads in flight under its
// MFMA burst (lgkmcnt(6), not 0); setprio(1) wraps each MFMA batch (T5).
template <int CIN, bool FUSE_DS>
__global__ __launch_bounds__(512, 2) void conv3x3(
    const unsigned short* __restrict__ src,  // [8][128][CIN/8][130][8]
    const unsigned short* __restrict__ wt,   // [cic][p][tap][co][8]
    const float* __restrict__ bias,          // [128]
    const unsigned short* __restrict__ zp,   // zeroed 8KB
    unsigned short* __restrict__ dst_bf16,   // [8][128][16][130][8]
    float* __restrict__ dst_f32,             // NCHW fp32 [8,128,128,128]
    const float* __restrict__ wds,           // [2,128] (FUSE_DS)
    const int* __restrict__ tar,             // [8,128,128] (FUSE_DS)
    float* __restrict__ ds,                  // [8,2,128,128] (FUSE_DS)
    float* __restrict__ amap) {              // [8,128,128] (FUSE_DS)
  constexpr int CPG = CIN / 8;
  constexpr int NC = CIN / 16;
  // input plane padded to 832 slots (13 ops x 64); 6 halo rows x 130 used.
  __shared__ unsigned short in_tile[2][1664 * 8];  // 2 x 26 KB
  __shared__ unsigned short wt_tile[2][2304 * 8];  // 2 x 36.9 KB
  __shared__ unsigned short scr[64 * 8];           // dummy-op sink, 1 KB
  __shared__ float sb[128];
  __shared__ float w0s[128], w1s[128];
  __shared__ float sc[4 * 4 * 2 * 32];

  const int tid = threadIdx.x;
  const int b = blockIdx.x >> 5;
  const int y0 = (blockIdx.x & 31) * 4;
  const int lane = tid & 63, wave = tid >> 6;
  const int wco = wave & 1, wrow = wave >> 1;
  const int l31 = lane & 31, kh = lane >> 5;

  if (tid < 128) {
    sb[tid] = bias[tid];
    if constexpr (FUSE_DS) {
      w0s[tid] = wds[tid];
      w1s[tid] = wds[128 + tid];
    }
  }

  // ---- flat op table: ops 0..35 = wt slab, 36..61 = input, 62..63 dummy
  const unsigned short* gb[8];
  unsigned short* ld0[8];
  int gst[8];
  int lst[8];
#pragma unroll
  for (int i = 0; i < 8; ++i) {
    const int o = wave * 8 + i;
    if (o < 36) {
      gb[i] = wt + o * 512 + lane * 8;
      gst[i] = 18432;
      ld0[i] = &wt_tile[0][(size_t)o * 512];
      lst[i] = 18432;
    } else if (o < 62) {
      const int q = o - 36;
      const int p = q / 13, j = q - p * 13;
      const int s = j * 64 + lane;
      const int hy = s / 130, hx = s - hy * 130;
      const int gy = y0 - 1 + hy;
      const bool ok = (s < 780) && (gy >= 0) && (gy < 128);
      gb[i] = ok ? src + ((size_t)((b * 128 + gy) * CPG) + p) * 1040 + hx * 8
                 : zp + lane * 8;
      gst[i] = ok ? 2080 : 0;
      ld0[i] = &in_tile[0][(size_t)(p * 832 + j * 64) * 8];
      lst[i] = 1664 * 8;
    } else {
      gb[i] = zp + lane * 8;
      gst[i] = 0;
      ld0[i] = &scr[0];
      lst[i] = 0;
    }
  }

  f32x16 acc[2][4] = {};

  // prologue: stage chunk 0 into buf 0
#pragma unroll
  for (int i = 0; i < 8; ++i) gl_lds16(gb[i], ld0[i]);
  VMCNT0;
  LGKM0;
  BAR;
  SCHEDB;

  for (int cic = 0; cic < NC; ++cic) {
    const int cur = cic & 1;
    const bool more = (cic + 1 < NC);
    if (more) {
      const int nb = cur ^ 1;
#pragma unroll
      for (int i = 0; i < 8; ++i)
        gl_lds16(gb[i] + (size_t)(cic + 1) * gst[i],
                 ld0[i] + (size_t)nb * lst[i]);
      SCHEDB;
      VMCNT8;  // waits only for chunk-k ops (issued last iter, already landed)
    } else {
      VMCNT0;
    }
    SCHEDB;
    BAR;  // B1: chunk k fully staged for all waves
    SCHEDB;

    // ---- compute chunk k: 2-deep tap pipeline, two named register sets
    const unsigned short* it = &in_tile[cur][0];
    const unsigned short* wl = &wt_tile[cur][0];
    const size_t ib = (size_t)kh * (832 * 8);
    const size_t wb = (size_t)kh * 9216;

    bf16x8 xa0, xa1, xb0, xb1, xb2, xb3;  // even-tap set
    bf16x8 ya0, ya1, yb0, yb1, yb2, yb3;  // odd-tap set

#define LD_TAP(T, A0, A1, B0, B1, B2, B3)                                      \
  {                                                                            \
    constexpr int ky_ = (T) / 3, kx_ = (T) % 3;                                \
    const int hy_ = ky_ + wrow;                                                \
    A0 = *(const bf16x8*)(&wl[wb + (size_t)((T)*128 + wco * 64 + l31) * 8]);   \
    A1 = *(const bf16x8*)(&wl[wb + (size_t)((T)*128 + wco * 64 + 32 + l31) * 8]); \
    B0 = *(const bf16x8*)(&it[ib + (size_t)(hy_ * 130 + l31 + kx_) * 8]);      \
    B1 = *(const bf16x8*)(&it[ib + (size_t)(hy_ * 130 + 32 + l31 + kx_) * 8]); \
    B2 = *(const bf16x8*)(&it[ib + (size_t)(hy_ * 130 + 64 + l31 + kx_) * 8]); \
    B3 = *(const bf16x8*)(&it[ib + (size_t)(hy_ * 130 + 96 + l31 + kx_) * 8]); \
  }

#define MFMA_TAP(A0, A1, B0, B1, B2, B3)                                       \
  {                                                                            \
    PRIO1;                                                                     \
    acc[0][0] = __builtin_amdgcn_mfma_f32_32x32x16_bf16(A0, B0, acc[0][0], 0, 0, 0); \
    acc[0][1] = __builtin_amdgcn_mfma_f32_32x32x16_bf16(A0, B1, acc[0][1], 0, 0, 0); \
    acc[0][2] = __builtin_amdgcn_mfma_f32_32x32x16_bf16(A0, B2, acc[0][2], 0, 0, 0); \
    acc[0][3] = __builtin_amdgcn_mfma_f32_32x32x16_bf16(A0, B3, acc[0][3], 0, 0, 0); \
    acc[1][0] = __builtin_amdgcn_mfma_f32_32x32x16_bf16(A1, B0, acc[1][0], 0, 0, 0); \
    acc[1][1] = __builtin_amdgcn_mfma_f32_32x32x16_bf16(A1, B1, acc[1][1], 0, 0, 0); \
    acc[1][2] = __builtin_amdgcn_mfma_f32_32x32x16_bf16(A1, B2, acc[1][2], 0, 0, 0); \
    acc[1][3] = __builtin_amdgcn_mfma_f32_32x32x16_bf16(A1, B3, acc[1][3], 0, 0, 0); \
    PRIO0;                                                                     \
  }

    LD_TAP(0, xa0, xa1, xb0, xb1, xb2, xb3);
    LD_TAP(1, ya0, ya1, yb0, yb1, yb2, yb3);
    SCHEDB;
    MFMA_TAP(xa0, xa1, xb0, xb1, xb2, xb3);   // tap 0
    LD_TAP(2, xa0, xa1, xb0, xb1, xb2, xb3);
    SCHEDB;
    MFMA_TAP(ya0, ya1, yb0, yb1, yb2, yb3);   // tap 1
    LD_TAP(3, ya0, ya1, yb0, yb1, yb2, yb3);
    SCHEDB;
    MFMA_TAP(xa0, xa1, xb0, xb1, xb2, xb3);   // tap 2
    LD_TAP(4, xa0, xa1, xb0, xb1, xb2, xb3);
    SCHEDB;
    MFMA_TAP(ya0, ya1, yb0, yb1, yb2, yb3);   // tap 3
    LD_TAP(5, ya0, ya1, yb0, yb1, yb2, yb3);
    SCHEDB;
    MFMA_TAP(xa0, xa1, xb0, xb1, xb2, xb3);   // tap 4
    LD_TAP(6, xa0, xa1, xb0, xb1, xb2, xb3);
    SCHEDB;
    MFMA_TAP(ya0, ya1, yb0, yb1, yb2, yb3);   // tap 5
    LD_TAP(7, ya0, ya1, yb0, yb1, yb2, yb3);
    SCHEDB;
    MFMA_TAP(xa0, xa1, xb0, xb1, xb2, xb3);   // tap 6
    LD_TAP(8, xa0, xa1, xb0, xb1, xb2, xb3);
    SCHEDB;
    MFMA_TAP(ya0, ya1, yb0, yb1, yb2, yb3);   // tap 7
    SCHEDB;
    MFMA_TAP(xa0, xa1, xb0, xb1, xb2, xb3);   // tap 8
#undef LD_TAP
#undef MFMA_TAP

    SCHEDB;
    LGKM0;  // my ds_reads retired (free: all waited before last MFMA)
    BAR;    // B2: buffers safe to overwrite next iteration
    SCHEDB;
  }

  // ---- epilogue. D: col(px)=lane&31, row(co)=(r&3)+8*(r>>2)+4*kh
  const int gyo = y0 + wrow;
  float pd[4][2] = {};  // [fp][cls] (FUSE_DS)
#pragma unroll
  for (int fc = 0; fc < 2; ++fc) {
#pragma unroll
    for (int fp = 0; fp < 4; ++fp) {
      const int px = fp * 32 + l31;
      if constexpr (!FUSE_DS) {
#pragma unroll
        for (int rg = 0; rg < 4; ++rg) {
          const int co0 = wco * 64 + fc * 32 + rg * 8 + kh * 4;
          unsigned short pk[4];
#pragma unroll
          for (int q = 0; q < 4; ++q) {
            float v = acc[fc][fp][rg * 4 + q] + sb[co0 + q];
            v = v > 0.f ? v : 0.01f * v;
            pk[q] = f2bf(v);
          }
          uint2 o;
          o.x = (unsigned)pk[0] | ((unsigned)pk[1] << 16);
          o.y = (unsigned)pk[2] | ((unsigned)pk[3] << 16);
          *(uint2*)(&dst_bf16[(((long)(b * 128 + gyo) * 16 + (co0 >> 3)) * 130 + px + 1) * 8 +
                              kh * 4]) = o;
        }
      } else {
#pragma unroll
        for (int rg = 0; rg < 4; ++rg) {
          const int co0 = wco * 64 + fc * 32 + rg * 8 + kh * 4;
          float4 wv0 = *(const float4*)(&w0s[co0]);
          float4 wv1 = *(const float4*)(&w1s[co0]);
#pragma unroll
          for (int q = 0; q < 4; ++q) {
            float v = acc[fc][fp][rg * 4 + q] + sb[co0 + q];
            v = v > 0.f ? v : 0.01f * v;
            dst_f32[((long)(b * 128 + co0 + q) << 14) + (gyo << 7) + px] = v;
            float wq0 = (q == 0) ? wv0.x : (q == 1) ? wv0.y : (q == 2) ? wv0.z : wv0.w;
            float wq1 = (q == 0) ? wv1.x : (q == 1) ? wv1.y : (q == 2) ? wv1.z : wv1.w;
            pd[fp][0] += wq0 * v;
            pd[fp][1] += wq1 * v;
          }
        }
      }
    }
  }

  if constexpr (!FUSE_DS) {  // zero px 0,129 of this block's 4 rows, all cig
    if (tid < 128) {
      int row = tid >> 5, g = (tid >> 1) & 15;
      long col = (tid & 1) * 129L;
      *(uint4*)(&dst_bf16[(((long)(b * 128 + y0 + row) * 16 + g) * 130 + col) * 8]) =
          make_uint4(0, 0, 0, 0);
    }
  } else {
    // reduce kh (lane^32), then wco pairs via LDS scratch
#pragma unroll
    for (int fp = 0; fp < 4; ++fp)
#pragma unroll
      for (int c = 0; c < 2; ++c)
        pd[fp][c] += __shfl_xor(pd[fp][c], 32, 64);
    if (wco == 1 && kh == 0) {
#pragma unroll
      for (int fp = 0; fp < 4; ++fp)
#pragma unroll
        for (int c = 0; c < 2; ++c)
          sc[((wrow * 4 + fp) * 2 + c) * 32 + l31] = pd[fp][c];
    }
    __syncthreads();
    if (wco == 0 && kh == 0) {
      const int* tb = tar + (long)b * 16384;
#pragma unroll
      for (int fp = 0; fp < 4; ++fp) {
        const int px = fp * 32 + l31;
        float a0 = pd[fp][0] + sc[((wrow * 4 + fp) * 2 + 0) * 32 + l31];
        float a1 = pd[fp][1] + sc[((wrow * 4 + fp) * 2 + 1) * 32 + l31];
        ds[((long)b * 2) * 16384 + (gyo << 7) + px] = a0;
        ds[((long)b * 2 + 1) * 16384 + (gyo << 7) + px] = a1;
        float m = fmaxf(a0, a1);
        float e0 = expf(a0 - m), e1 = expf(a1 - m);
        float s = e0 + e1;
        float p0f = e0 / s, p1f = e1 / s;
        float ent = -(p0f * log2f(p0f + 1e-6f) + p1f * log2f(p1f + 1e-6f));
        float un = ent >= 0.001f ? 1.f : 0.f;
        float pro = 1.f;
        if (gyo > 0 && gyo < 127 && px > 0 && px < 127) {
          int c = tb[(gyo << 7) + px];
          if (c != 0) {
            int nb2 = tb[((gyo - 1) << 7) + px] + tb[((gyo + 1) << 7) + px] +
                      tb[(gyo << 7) + px - 1] + tb[(gyo << 7) + px + 1];
            if (4 * c != nb2) pro = 0.f;
          }
        }
        amap[((long)(b * 128 + gyo) << 7) + px] = un * pro;
      }
    }
  }
}

extern "C" void kernel_launch(void* const* d_in, const int* in_sizes, int n_in,
                              void* d_out, int out_size, void* d_ws, size_t ws_size,
                              hipStream_t stream) {
  const float* x    = (const float*)d_in[0];
  const float* skip = (const float*)d_in[1];
  const int*   tar  = (const int*)d_in[2];
  const float* W1   = (const float*)d_in[3];
  const float* b1   = (const float*)d_in[4];
  const float* W2   = (const float*)d_in[5];
  const float* b2   = (const float*)d_in[6];
  const float* Wds  = (const float*)d_in[7];

  float* out_h  = (float*)d_out;            // 16777216 f32 (h, NCHW)
  float* out_ds = out_h + 16777216;         // 262144 f32
  float* out_am = out_ds + 262144;          // 131072 f32

  // ws: W1b | W2b | zp | (1MB) h1  [8][128][16][130][8] bf16 (34.1MB)
  unsigned short* W1b = (unsigned short*)d_ws;
  unsigned short* W2b = W1b + 294912;
  unsigned short* zp  = W2b + 147456;
  unsigned short* h1  = (unsigned short*)((char*)d_ws + (1u << 20));

  // h0: [8][128][32][130][8] bf16 = 68.2MB, lives in d_out (68.7MB);
  // fully dead before conv2 overwrites d_out (h/ds/amap regions).
  unsigned short* h0 = (unsigned short*)d_out;

  convert_weights<<<1729, 256, 0, stream>>>(W1, W2, W1b, W2b, zp);
  transpose_to_bf16<<<1024, 256, 0, stream>>>(x, h0, 0);
  transpose_to_bf16<<<1024, 256, 0, stream>>>(skip, h0, 16);
  conv3x3<256, false><<<256, 512, 0, stream>>>(h0, W1b, b1, zp, h1, nullptr,
                                               nullptr, nullptr, nullptr, nullptr);
  conv3x3<128, true><<<256, 512, 0, stream>>>(h1, W2b, b2, zp, nullptr, out_h,
                                              Wds, tar, out_ds, out_am);
}